// Round 3
// baseline (317.423 us; speedup 1.0000x reference)
//
#include <hip/hip_runtime.h>
#include <hip/hip_bf16.h>
#include <math.h>

#define INDIM 768
#define NROWS 32768       // 8*4096
#define KSEL  38
#define NCOLS 76
#define CPAD  96
#define HID   256
#define NPADJ 80
#define LN_EPS 1e-5f

typedef float  f32x4  __attribute__((ext_vector_type(4)));
typedef __bf16 bf16x8 __attribute__((ext_vector_type(8)));

#define MFMA16(a,b,c) __builtin_amdgcn_mfma_f32_16x16x32_bf16((a),(b),(c),0,0,0)

// ws layout (bytes)
#define OFF_BFT 0
#define OFF_BST 147456
#define OFF_W1B 294912
#define OFF_W2T 393216

__global__ void k_prep(const int* __restrict__ idxs,
                       const float* __restrict__ mu_w1, const float* __restrict__ sg_w1,
                       const float* __restrict__ mu_w2, const float* __restrict__ sg_w2,
                       __bf16* __restrict__ Bft, __bf16* __restrict__ Bst,
                       __bf16* __restrict__ W1b, __bf16* __restrict__ W2t)
{
    int tid = blockIdx.x * blockDim.x + threadIdx.x;
    int nth = gridDim.x * blockDim.x;
    const float TH = 6.28318530717958647692f / (float)INDIM;

    for (int i = tid; i < CPAD * INDIM; i += nth) {
        int c = i / INDIM, n = i % INDIM;
        float v = 0.f;
        if (c < NCOLS) {
            int cc = (c < KSEL) ? c : c - KSEL;
            int f = idxs[cc];
            int m = (f * n) % INDIM;
            float s, co; sincosf(TH * (float)m, &s, &co);
            v = (c < KSEL) ? co : -s;
        }
        Bft[i] = (__bf16)v;
    }
    for (int i = tid; i < INDIM * CPAD; i += nth) {
        int n = i / CPAD, c = i % CPAD;
        float v = 0.f;
        if (c < NCOLS) {
            int cc = (c < KSEL) ? c : c - KSEL;
            int f = idxs[cc];
            int m = (f * n) % INDIM;
            float s, co; sincosf(TH * (float)m, &s, &co);
            v = ((c < KSEL) ? co : -s) * (2.0f / (float)INDIM);
        }
        Bst[i] = (__bf16)v;
    }
    for (int i = tid; i < 2 * HID * CPAD; i += nth) {
        int mlp = i / (HID * CPAD); int rem = i % (HID * CPAD);
        int r = rem / CPAD, k = rem % CPAD;
        const float* W = mlp ? sg_w1 : mu_w1;
        W1b[i] = (__bf16)((k < NCOLS) ? W[r * NCOLS + k] : 0.f);
    }
    for (int i = tid; i < 2 * NPADJ * HID; i += nth) {
        int mlp = i / (NPADJ * HID); int rem = i % (NPADJ * HID);
        int j = rem / HID, h = rem % HID;
        const float* W = mlp ? sg_w2 : mu_w2;
        W2t[i] = (__bf16)((j < NCOLS) ? W[j * HID + h] : 0.f);
    }
}

static __device__ inline float gelu_exact(float v) {
    return v * 0.5f * (1.f + erff(v * 0.70710678118654752440f));
}

// Fused: DFT -> MLPx2 -> z -> synthesis. One wave owns 16 rows.
// Shared matrices (Bft/W1/W2/Bst) are block-cooperatively staged into a
// double-buffered LDS region (one barrier per chunk); MFMA B-operands come
// from ds_read_b128. x streams through registers with 1-chunk prefetch.
// LDS: stage 2*6912*2 = 27648 B + wave bufs 4*4224*2 = 33792 B => 61440 B
//   -> 2 blocks/CU (122880 <= 160K).
__global__ __launch_bounds__(256, 2) void k_fused(
    const float* __restrict__ x, const float* __restrict__ eps,
    const __bf16* __restrict__ Bft, const __bf16* __restrict__ Bst,
    const __bf16* __restrict__ W1b, const __bf16* __restrict__ W2t,
    const float* __restrict__ mu_b1, const float* __restrict__ mu_g,
    const float* __restrict__ mu_be, const float* __restrict__ mu_b2,
    const float* __restrict__ sg_b1, const float* __restrict__ sg_g,
    const float* __restrict__ sg_be, const float* __restrict__ sg_b2,
    float* __restrict__ out)
{
    __shared__ __bf16 stg[2][6912];
    __shared__ __bf16 sbuf[4 * 4224];
    int tid = threadIdx.x;
    int w = tid >> 6, lane = tid & 63, q = lane >> 4, l16 = lane & 15;
    int rbase = blockIdx.x * 64 + w * 16;
    __bf16* buf = &sbuf[w * 4224];

    // --- staging helpers (block-uniform) ---
    // 96 rows x 64 cols, LDS stride 72 (row*144B: 16B aligned, 2-way banks)
    auto ld72 = [&](const __bf16* src, bf16x8* r) {
        #pragma unroll
        for (int i = 0; i < 3; ++i) {
            int g = tid + i * 256; int row = g >> 3, seg = (g & 7) * 8;
            r[i] = *(const bf16x8*)&src[(size_t)row * INDIM + seg];
        }
    };
    auto st72 = [&](__bf16* dst, const bf16x8* r) {
        #pragma unroll
        for (int i = 0; i < 3; ++i) {
            int g = tid + i * 256; int row = g >> 3, seg = (g & 7) * 8;
            *(bf16x8*)&dst[row * 72 + seg] = r[i];
        }
    };
    // 64 rows x 96 cols (src stride 96), LDS stride 104
    auto ld104 = [&](const __bf16* src, bf16x8* r) {
        #pragma unroll
        for (int i = 0; i < 3; ++i) {
            int g = tid + i * 256; int row = g / 12, seg = (g % 12) * 8;
            r[i] = *(const bf16x8*)&src[(size_t)row * 96 + seg];
        }
    };
    auto st104 = [&](__bf16* dst, const bf16x8* r) {
        #pragma unroll
        for (int i = 0; i < 3; ++i) {
            int g = tid + i * 256; int row = g / 12, seg = (g % 12) * 8;
            *(bf16x8*)&dst[row * 104 + seg] = r[i];
        }
    };
    // 16 rows x 256 cols (src stride 256), LDS stride 264
    auto ld264 = [&](const __bf16* src, bf16x8* r) {
        #pragma unroll
        for (int i = 0; i < 2; ++i) {
            int g = tid + i * 256; int row = g >> 5, seg = (g & 31) * 8;
            r[i] = *(const bf16x8*)&src[(size_t)row * 256 + seg];
        }
    };
    auto st264 = [&](__bf16* dst, const bf16x8* r) {
        #pragma unroll
        for (int i = 0; i < 2; ++i) {
            int g = tid + i * 256; int row = g >> 5, seg = (g & 31) * 8;
            *(bf16x8*)&dst[row * 264 + seg] = r[i];
        }
    };

    // ---------------- Phase 1: DFT, K=768 in 12 chunks of 64 ----------------
    f32x4 acc[6] = {};
    {
        const float* xrow = x + (size_t)(rbase + l16) * INDIM + q * 8;
        bf16x8 sreg[3];
        ld72(Bft, sreg); st72(stg[0], sreg);
        float4 xf[4];
        xf[0] = ((const float4*)xrow)[0];       xf[1] = ((const float4*)xrow)[1];
        xf[2] = ((const float4*)(xrow + 32))[0]; xf[3] = ((const float4*)(xrow + 32))[1];
        __syncthreads();
        for (int kc = 0; kc < 12; ++kc) {
            bf16x8 nreg[3]; float4 xn[4];
            if (kc + 1 < 12) {
                ld72(Bft + (kc + 1) * 64, nreg);
                const float* xp = xrow + (kc + 1) * 64;
                xn[0] = ((const float4*)xp)[0];       xn[1] = ((const float4*)xp)[1];
                xn[2] = ((const float4*)(xp + 32))[0]; xn[3] = ((const float4*)(xp + 32))[1];
            }
            const __bf16* S = stg[kc & 1];
            #pragma unroll
            for (int ks = 0; ks < 2; ++ks) {
                float4 f0 = xf[ks * 2], f1 = xf[ks * 2 + 1];
                union { __bf16 h[8]; bf16x8 v; } a;
                a.h[0]=(__bf16)f0.x; a.h[1]=(__bf16)f0.y; a.h[2]=(__bf16)f0.z; a.h[3]=(__bf16)f0.w;
                a.h[4]=(__bf16)f1.x; a.h[5]=(__bf16)f1.y; a.h[6]=(__bf16)f1.z; a.h[7]=(__bf16)f1.w;
                #pragma unroll
                for (int nt = 0; nt < 6; ++nt) {
                    bf16x8 b = *(const bf16x8*)&S[(nt * 16 + l16) * 72 + ks * 32 + q * 8];
                    acc[nt] = MFMA16(a.v, b, acc[nt]);
                }
            }
            if (kc + 1 < 12) {
                st72(stg[(kc + 1) & 1], nreg);
                xf[0]=xn[0]; xf[1]=xn[1]; xf[2]=xn[2]; xf[3]=xn[3];
            }
            __syncthreads();
        }
    }
    // D-layout transpose -> a1 frags (wave-private buf, no barrier needed)
    #pragma unroll
    for (int nt = 0; nt < 6; ++nt)
        #pragma unroll
        for (int r = 0; r < 4; ++r)
            buf[(q * 4 + r) * 104 + nt * 16 + l16] = (__bf16)acc[nt][r];
    bf16x8 a1[3];
    #pragma unroll
    for (int ks = 0; ks < 3; ++ks)
        a1[ks] = *(const bf16x8*)&buf[l16 * 104 + ks * 32 + q * 8];

    // ---------------- Phase 2+3: MLPs (sequential) ----------------
    f32x4 o2[2][5];
    #pragma unroll
    for (int mlp = 0; mlp < 2; ++mlp) {
        const __bf16* W1m = W1b + (size_t)mlp * HID * CPAD;
        const __bf16* W2m = W2t + (size_t)mlp * NPADJ * HID;
        const float* b1 = mlp ? sg_b1 : mu_b1;
        const float* g  = mlp ? sg_g  : mu_g;
        const float* be = mlp ? sg_be : mu_be;

        // layer1: 4 chunks of 64 hidden rows
        f32x4 h[16] = {};
        {
            bf16x8 sreg[3];
            ld104(W1m, sreg); st104(stg[0], sreg);
            __syncthreads();
            for (int c = 0; c < 4; ++c) {
                bf16x8 nreg[3];
                if (c + 1 < 4) ld104(W1m + (size_t)(c + 1) * 64 * 96, nreg);
                const __bf16* S = stg[c & 1];
                #pragma unroll
                for (int ntl = 0; ntl < 4; ++ntl)
                    #pragma unroll
                    for (int ks = 0; ks < 3; ++ks) {
                        bf16x8 b = *(const bf16x8*)&S[(ntl * 16 + l16) * 104 + ks * 32 + q * 8];
                        h[c * 4 + ntl] = MFMA16(a1[ks], b, h[c * 4 + ntl]);
                    }
                if (c + 1 < 4) st104(stg[(c + 1) & 1], nreg);
                __syncthreads();
            }
        }
        // bias + LN stats
        float s[4] = {}, ss[4] = {};
        #pragma unroll
        for (int nt = 0; nt < 16; ++nt) {
            float bb = b1[nt * 16 + l16];
            #pragma unroll
            for (int r = 0; r < 4; ++r) {
                float v = h[nt][r] + bb; h[nt][r] = v;
                s[r] += v; ss[r] += v * v;
            }
        }
        #pragma unroll
        for (int off = 1; off < 16; off <<= 1)
            #pragma unroll
            for (int r = 0; r < 4; ++r) {
                s[r] += __shfl_xor(s[r], off); ss[r] += __shfl_xor(ss[r], off);
            }
        float mean[4], rstd[4];
        #pragma unroll
        for (int r = 0; r < 4; ++r) {
            mean[r] = s[r] * (1.f / 256.f);
            rstd[r] = rsqrtf(ss[r] * (1.f / 256.f) - mean[r] * mean[r] + LN_EPS);
        }
        // LN + gelu -> wave buf (stride 264) -> a2 frags
        #pragma unroll
        for (int nt = 0; nt < 16; ++nt) {
            int i = nt * 16 + l16;
            float gv = g[i], bev = be[i];
            #pragma unroll
            for (int r = 0; r < 4; ++r)
                buf[(q * 4 + r) * 264 + i] =
                    (__bf16)gelu_exact((h[nt][r] - mean[r]) * rstd[r] * gv + bev);
        }
        bf16x8 a2[8];
        #pragma unroll
        for (int ks = 0; ks < 8; ++ks)
            a2[ks] = *(const bf16x8*)&buf[l16 * 264 + ks * 32 + q * 8];

        // layer2: 5 chunks of 16 out rows
        {
            bf16x8 sreg[2];
            ld264(W2m, sreg); st264(stg[0], sreg);
            __syncthreads();
            for (int nt = 0; nt < 5; ++nt) {
                bf16x8 nreg[2];
                if (nt + 1 < 5) ld264(W2m + (size_t)(nt + 1) * 16 * 256, nreg);
                const __bf16* S = stg[nt & 1];
                f32x4 oc = {};
                #pragma unroll
                for (int ks = 0; ks < 8; ++ks) {
                    bf16x8 b = *(const bf16x8*)&S[l16 * 264 + ks * 32 + q * 8];
                    oc = MFMA16(a2[ks], b, oc);
                }
                o2[mlp][nt] = oc;
                if (nt + 1 < 5) st264(stg[(nt + 1) & 1], nreg);
                __syncthreads();
            }
        }
    }

    // ---------------- Phase 4: z = mu + eps*sg -> wave buf ----------------
    #pragma unroll
    for (int nt = 0; nt < 5; ++nt) {
        int j = nt * 16 + l16;
        float b2m = (j < NCOLS) ? mu_b2[j] : 0.f;
        float b2s = (j < NCOLS) ? sg_b2[j] : 0.f;
        #pragma unroll
        for (int r = 0; r < 4; ++r) {
            float z = 0.f;
            if (j < NCOLS) {
                float e = eps[(size_t)(rbase + q * 4 + r) * NCOLS + j];
                z = (o2[0][nt][r] + b2m) + e * (o2[1][nt][r] + b2s);
            }
            buf[(q * 4 + r) * 104 + j] = (__bf16)z;
        }
    }
    #pragma unroll
    for (int r = 0; r < 4; ++r)
        buf[(q * 4 + r) * 104 + 80 + l16] = (__bf16)0.f;
    bf16x8 az[3];
    #pragma unroll
    for (int ks = 0; ks < 3; ++ks)
        az[ks] = *(const bf16x8*)&buf[l16 * 104 + ks * 32 + q * 8];

    // ---------------- Phase 5: synthesis, 12 chunks of 64 out-cols ----------------
    {
        bf16x8 sreg[3];
        ld104(Bst, sreg); st104(stg[0], sreg);
        __syncthreads();
        for (int c = 0; c < 12; ++c) {
            bf16x8 nreg[3];
            if (c + 1 < 12) ld104(Bst + (size_t)(c + 1) * 64 * 96, nreg);
            const __bf16* S = stg[c & 1];
            #pragma unroll
            for (int ntl = 0; ntl < 4; ++ntl) {
                f32x4 oc = {};
                #pragma unroll
                for (int ks = 0; ks < 3; ++ks) {
                    bf16x8 b = *(const bf16x8*)&S[(ntl * 16 + l16) * 104 + ks * 32 + q * 8];
                    oc = MFMA16(az[ks], b, oc);
                }
                int col = (c * 4 + ntl) * 16 + l16;
                #pragma unroll
                for (int r = 0; r < 4; ++r)
                    out[(size_t)(rbase + q * 4 + r) * INDIM + col] = oc[r];
            }
            if (c + 1 < 12) st104(stg[(c + 1) & 1], nreg);
            __syncthreads();
        }
    }
}

extern "C" void kernel_launch(void* const* d_in, const int* in_sizes, int n_in,
                              void* d_out, int out_size, void* d_ws, size_t ws_size,
                              hipStream_t stream)
{
    const float* x     = (const float*)d_in[0];
    const float* eps   = (const float*)d_in[1];
    const int*   idxs  = (const int*)  d_in[2];
    const float* mu_w1 = (const float*)d_in[3];
    const float* mu_b1 = (const float*)d_in[4];
    const float* mu_g  = (const float*)d_in[5];
    const float* mu_be = (const float*)d_in[6];
    const float* mu_w2 = (const float*)d_in[7];
    const float* mu_b2 = (const float*)d_in[8];
    const float* sg_w1 = (const float*)d_in[9];
    const float* sg_b1 = (const float*)d_in[10];
    const float* sg_g  = (const float*)d_in[11];
    const float* sg_be = (const float*)d_in[12];
    const float* sg_w2 = (const float*)d_in[13];
    const float* sg_b2 = (const float*)d_in[14];
    float* out = (float*)d_out;

    char* ws = (char*)d_ws;
    __bf16* Bft = (__bf16*)(ws + OFF_BFT);
    __bf16* Bst = (__bf16*)(ws + OFF_BST);
    __bf16* W1b = (__bf16*)(ws + OFF_W1B);
    __bf16* W2t = (__bf16*)(ws + OFF_W2T);

    hipLaunchKernelGGL(k_prep, dim3(512), dim3(256), 0, stream,
                       idxs, mu_w1, sg_w1, mu_w2, sg_w2, Bft, Bst, W1b, W2t);
    hipLaunchKernelGGL(k_fused, dim3(NROWS / 64), dim3(256), 0, stream,
                       x, eps, Bft, Bst, W1b, W2t,
                       mu_b1, mu_g, mu_be, mu_b2,
                       sg_b1, sg_g, sg_be, sg_b2, out);
}

// Round 4
// 300.071 us; speedup vs baseline: 1.0578x; 1.0578x over previous
//
#include <hip/hip_runtime.h>
#include <hip/hip_bf16.h>
#include <math.h>

#define INDIM 768
#define NROWS 32768       // 8*4096
#define KSEL  38
#define NCOLS 76
#define CPAD  96
#define HID   256
#define LN_EPS 1e-5f

typedef float  f32x4  __attribute__((ext_vector_type(4)));
typedef __bf16 bf16x8 __attribute__((ext_vector_type(8)));

#define MFMA16(a,b,c) __builtin_amdgcn_mfma_f32_16x16x32_bf16((a),(b),(c),0,0,0)

// ---- workspace: all shared matrices pre-packed in MFMA B-fragment order ----
// frag layout: value(lane, j) = M[n = nt*16 + (lane&15)][k = ks*32 + (lane>>4)*8 + j]
// stored as [frag][lane][8] bf16 -> every B-operand load is 64 lanes x 16B CONTIGUOUS.
// BfP: DFT basis,  frag = kc*5 + nt   (kc 0..23, nt 0..4)   : 120 frags
// W1P: layer1 w,   frag = mlp*48 + nt*3 + ks (nt 0..15)     : 96 frags
// W2P: layer2 w,   frag = mlp*40 + nt*8 + ks (nt 0..4)      : 80 frags
// BsP: synth basis frag = nt*3 + ks  (nt 0..47)             : 144 frags
#define OFF_BFP 0
#define OFF_W1P 122880
#define OFF_W2P 221184
#define OFF_BSP 303104

__global__ void k_prep(const int* __restrict__ idxs,
                       const float* __restrict__ mu_w1, const float* __restrict__ sg_w1,
                       const float* __restrict__ mu_w2, const float* __restrict__ sg_w2,
                       __bf16* __restrict__ BfP, __bf16* __restrict__ W1P,
                       __bf16* __restrict__ W2P, __bf16* __restrict__ BsP)
{
    int tid = blockIdx.x * blockDim.x + threadIdx.x;
    int nth = gridDim.x * blockDim.x;
    const float TH = 6.28318530717958647692f / (float)INDIM;

    // BfP: 120 frags -> 61440 elems. row c = nt*16+(lane&15) (<=79), k = kc*32+(lane>>4)*8+j
    for (int e = tid; e < 120 * 512; e += nth) {
        int frag = e >> 9, lane = (e >> 3) & 63, j = e & 7;
        int kc = frag / 5, nt = frag % 5;
        int c = nt * 16 + (lane & 15);
        int k = kc * 32 + ((lane >> 4) << 3) + j;
        float v = 0.f;
        if (c < NCOLS) {
            int cc = (c < KSEL) ? c : c - KSEL;
            int f = idxs[cc];
            int m = (f * k) % INDIM;
            float s, co; sincosf(TH * (float)m, &s, &co);
            v = (c < KSEL) ? co : -s;
        }
        BfP[e] = (__bf16)v;
    }
    // W1P: 96 frags. row = nt*16+(lane&15) (0..255), k = ks*32+(lane>>4)*8+j (0..95)
    for (int e = tid; e < 96 * 512; e += nth) {
        int frag = e >> 9, lane = (e >> 3) & 63, j = e & 7;
        int mlp = frag / 48; int r = frag % 48;
        int nt = r / 3, ks = r % 3;
        int row = nt * 16 + (lane & 15);
        int k = ks * 32 + ((lane >> 4) << 3) + j;
        const float* W = mlp ? sg_w1 : mu_w1;
        W1P[e] = (__bf16)((k < NCOLS) ? W[row * NCOLS + k] : 0.f);
    }
    // W2P: 80 frags. row = nt*16+(lane&15) (0..79), k = ks*32+(lane>>4)*8+j (0..255)
    for (int e = tid; e < 80 * 512; e += nth) {
        int frag = e >> 9, lane = (e >> 3) & 63, j = e & 7;
        int mlp = frag / 40; int r = frag % 40;
        int nt = r / 8, ks = r % 8;
        int row = nt * 16 + (lane & 15);
        int k = ks * 32 + ((lane >> 4) << 3) + j;
        const float* W = mlp ? sg_w2 : mu_w2;
        W2P[e] = (__bf16)((row < NCOLS) ? W[row * HID + k] : 0.f);
    }
    // BsP: 144 frags. out-col n = nt*16+(lane&15) (0..767), k = coeff idx (0..95)
    for (int e = tid; e < 144 * 512; e += nth) {
        int frag = e >> 9, lane = (e >> 3) & 63, j = e & 7;
        int nt = frag / 3, ks = frag % 3;
        int n = nt * 16 + (lane & 15);
        int k = ks * 32 + ((lane >> 4) << 3) + j;
        float v = 0.f;
        if (k < NCOLS) {
            int cc = (k < KSEL) ? k : k - KSEL;
            int f = idxs[cc];
            int m = (f * n) % INDIM;
            float s, co; sincosf(TH * (float)m, &s, &co);
            v = ((k < KSEL) ? co : -s) * (2.0f / (float)INDIM);
        }
        BsP[e] = (__bf16)v;
    }
}

static __device__ inline float gelu_exact(float v) {
    return v * 0.5f * (1.f + erff(v * 0.70710678118654752440f));
}

// Fused DFT -> MLPx2 -> z -> synthesis. One wave owns 16 rows end-to-end.
// NO __syncthreads; LDS is wave-private transpose scratch only.
// All shared-matrix operands are coalesced sequential streams (packed frags).
__global__ __launch_bounds__(256, 2) void k_fused(
    const float* __restrict__ x, const float* __restrict__ eps,
    const bf16x8* __restrict__ Bf, const bf16x8* __restrict__ W1f,
    const bf16x8* __restrict__ W2f, const bf16x8* __restrict__ Bs,
    const float* __restrict__ mu_b1, const float* __restrict__ mu_g,
    const float* __restrict__ mu_be, const float* __restrict__ mu_b2,
    const float* __restrict__ sg_b1, const float* __restrict__ sg_g,
    const float* __restrict__ sg_be, const float* __restrict__ sg_b2,
    float* __restrict__ out)
{
    __shared__ __bf16 sbuf[4 * 4224];
    int tid = threadIdx.x;
    int w = tid >> 6, lane = tid & 63, q = lane >> 4, l16 = lane & 15;
    int rbase = blockIdx.x * 64 + w * 16;
    __bf16* buf = &sbuf[w * 4224];

    // ---------------- Phase 1: DFT (16 rows x 80 cols), K=768 ----------------
    f32x4 acc[5] = {};
    {
        const float* xrow = x + (size_t)(rbase + l16) * INDIM + q * 8;
        #pragma unroll
        for (int kc = 0; kc < 24; ++kc) {
            float4 f0 = ((const float4*)(xrow + kc * 32))[0];
            float4 f1 = ((const float4*)(xrow + kc * 32))[1];
            union { __bf16 h[8]; bf16x8 v; } a;
            a.h[0]=(__bf16)f0.x; a.h[1]=(__bf16)f0.y; a.h[2]=(__bf16)f0.z; a.h[3]=(__bf16)f0.w;
            a.h[4]=(__bf16)f1.x; a.h[5]=(__bf16)f1.y; a.h[6]=(__bf16)f1.z; a.h[7]=(__bf16)f1.w;
            #pragma unroll
            for (int nt = 0; nt < 5; ++nt) {
                bf16x8 b = Bf[(kc * 5 + nt) * 64 + lane];
                acc[nt] = MFMA16(a.v, b, acc[nt]);
            }
        }
    }
    // D-layout -> A-layout via wave-private LDS (stride 104); cols 80..95 zero
    #pragma unroll
    for (int nt = 0; nt < 5; ++nt)
        #pragma unroll
        for (int r = 0; r < 4; ++r)
            buf[(q * 4 + r) * 104 + nt * 16 + l16] = (__bf16)acc[nt][r];
    #pragma unroll
    for (int r = 0; r < 4; ++r)
        buf[(q * 4 + r) * 104 + 80 + l16] = (__bf16)0.f;
    bf16x8 a1[3];
    #pragma unroll
    for (int ks = 0; ks < 3; ++ks)
        a1[ks] = *(const bf16x8*)&buf[l16 * 104 + ks * 32 + q * 8];

    // ---------------- Phase 2: layer1, both MLPs interleaved ----------------
    f32x4 h0[16] = {}, h1[16] = {};
    #pragma unroll
    for (int nt = 0; nt < 16; ++nt) {
        #pragma unroll
        for (int ks = 0; ks < 3; ++ks) {
            bf16x8 b0 = W1f[(nt * 3 + ks) * 64 + lane];
            bf16x8 b1 = W1f[(48 + nt * 3 + ks) * 64 + lane];
            h0[nt] = MFMA16(a1[ks], b0, h0[nt]);
            h1[nt] = MFMA16(a1[ks], b1, h1[nt]);
        }
    }
    float s0[4] = {}, ss0[4] = {}, s1[4] = {}, ss1[4] = {};
    #pragma unroll
    for (int nt = 0; nt < 16; ++nt) {
        int i = nt * 16 + l16;
        float bb0 = mu_b1[i], bb1 = sg_b1[i];
        #pragma unroll
        for (int r = 0; r < 4; ++r) {
            float v0 = h0[nt][r] + bb0; h0[nt][r] = v0; s0[r] += v0; ss0[r] += v0 * v0;
            float v1 = h1[nt][r] + bb1; h1[nt][r] = v1; s1[r] += v1; ss1[r] += v1 * v1;
        }
    }
    #pragma unroll
    for (int off = 1; off < 16; off <<= 1)
        #pragma unroll
        for (int r = 0; r < 4; ++r) {
            s0[r] += __shfl_xor(s0[r], off);  ss0[r] += __shfl_xor(ss0[r], off);
            s1[r] += __shfl_xor(s1[r], off);  ss1[r] += __shfl_xor(ss1[r], off);
        }
    float mean0[4], rstd0[4], mean1[4], rstd1[4];
    #pragma unroll
    for (int r = 0; r < 4; ++r) {
        mean0[r] = s0[r] * (1.f / 256.f);
        rstd0[r] = rsqrtf(ss0[r] * (1.f / 256.f) - mean0[r] * mean0[r] + LN_EPS);
        mean1[r] = s1[r] * (1.f / 256.f);
        rstd1[r] = rsqrtf(ss1[r] * (1.f / 256.f) - mean1[r] * mean1[r] + LN_EPS);
    }
    // LN + gelu -> buf (stride 264) -> A-frags; mlp0 then mlp1 (wave-private reuse)
    bf16x8 a2[2][8];
    #pragma unroll
    for (int nt = 0; nt < 16; ++nt) {
        int i = nt * 16 + l16;
        float gv = mu_g[i], bev = mu_be[i];
        #pragma unroll
        for (int r = 0; r < 4; ++r)
            buf[(q * 4 + r) * 264 + i] =
                (__bf16)gelu_exact((h0[nt][r] - mean0[r]) * rstd0[r] * gv + bev);
    }
    #pragma unroll
    for (int ks = 0; ks < 8; ++ks)
        a2[0][ks] = *(const bf16x8*)&buf[l16 * 264 + ks * 32 + q * 8];
    #pragma unroll
    for (int nt = 0; nt < 16; ++nt) {
        int i = nt * 16 + l16;
        float gv = sg_g[i], bev = sg_be[i];
        #pragma unroll
        for (int r = 0; r < 4; ++r)
            buf[(q * 4 + r) * 264 + i] =
                (__bf16)gelu_exact((h1[nt][r] - mean1[r]) * rstd1[r] * gv + bev);
    }
    #pragma unroll
    for (int ks = 0; ks < 8; ++ks)
        a2[1][ks] = *(const bf16x8*)&buf[l16 * 264 + ks * 32 + q * 8];

    // ---------------- Phase 3: layer2, both MLPs interleaved ----------------
    f32x4 o[2][5] = {};
    #pragma unroll
    for (int nt = 0; nt < 5; ++nt) {
        #pragma unroll
        for (int ks = 0; ks < 8; ++ks) {
            bf16x8 b0 = W2f[(nt * 8 + ks) * 64 + lane];
            bf16x8 b1 = W2f[(40 + nt * 8 + ks) * 64 + lane];
            o[0][nt] = MFMA16(a2[0][ks], b0, o[0][nt]);
            o[1][nt] = MFMA16(a2[1][ks], b1, o[1][nt]);
        }
    }

    // ---------------- Phase 4: z = mu + eps*sg -> buf (stride 104) ----------------
    #pragma unroll
    for (int nt = 0; nt < 5; ++nt) {
        int j = nt * 16 + l16;
        float b2m = (j < NCOLS) ? mu_b2[j] : 0.f;
        float b2s = (j < NCOLS) ? sg_b2[j] : 0.f;
        #pragma unroll
        for (int r = 0; r < 4; ++r) {
            float z = 0.f;
            if (j < NCOLS) {
                float e = eps[(size_t)(rbase + q * 4 + r) * NCOLS + j];
                z = (o[0][nt][r] + b2m) + e * (o[1][nt][r] + b2s);
            }
            buf[(q * 4 + r) * 104 + j] = (__bf16)z;
        }
    }
    #pragma unroll
    for (int r = 0; r < 4; ++r)
        buf[(q * 4 + r) * 104 + 80 + l16] = (__bf16)0.f;
    bf16x8 az[3];
    #pragma unroll
    for (int ks = 0; ks < 3; ++ks)
        az[ks] = *(const bf16x8*)&buf[l16 * 104 + ks * 32 + q * 8];

    // ---------------- Phase 5: synthesis (16 rows x 768), write out ----------------
    #pragma unroll 8
    for (int nt = 0; nt < 48; ++nt) {
        f32x4 oc = {};
        #pragma unroll
        for (int ks = 0; ks < 3; ++ks) {
            bf16x8 b = Bs[(nt * 3 + ks) * 64 + lane];
            oc = MFMA16(az[ks], b, oc);
        }
        #pragma unroll
        for (int r = 0; r < 4; ++r)
            out[(size_t)(rbase + q * 4 + r) * INDIM + nt * 16 + l16] = oc[r];
    }
}

extern "C" void kernel_launch(void* const* d_in, const int* in_sizes, int n_in,
                              void* d_out, int out_size, void* d_ws, size_t ws_size,
                              hipStream_t stream)
{
    const float* x     = (const float*)d_in[0];
    const float* eps   = (const float*)d_in[1];
    const int*   idxs  = (const int*)  d_in[2];
    const float* mu_w1 = (const float*)d_in[3];
    const float* mu_b1 = (const float*)d_in[4];
    const float* mu_g  = (const float*)d_in[5];
    const float* mu_be = (const float*)d_in[6];
    const float* mu_w2 = (const float*)d_in[7];
    const float* mu_b2 = (const float*)d_in[8];
    const float* sg_w1 = (const float*)d_in[9];
    const float* sg_b1 = (const float*)d_in[10];
    const float* sg_g  = (const float*)d_in[11];
    const float* sg_be = (const float*)d_in[12];
    const float* sg_w2 = (const float*)d_in[13];
    const float* sg_b2 = (const float*)d_in[14];
    float* out = (float*)d_out;

    char* ws = (char*)d_ws;
    __bf16* BfP = (__bf16*)(ws + OFF_BFP);
    __bf16* W1P = (__bf16*)(ws + OFF_W1P);
    __bf16* W2P = (__bf16*)(ws + OFF_W2P);
    __bf16* BsP = (__bf16*)(ws + OFF_BSP);

    hipLaunchKernelGGL(k_prep, dim3(256), dim3(256), 0, stream,
                       idxs, mu_w1, sg_w1, mu_w2, sg_w2, BfP, W1P, W2P, BsP);
    hipLaunchKernelGGL(k_fused, dim3(NROWS / 64), dim3(256), 0, stream,
                       x, eps, (const bf16x8*)BfP, (const bf16x8*)W1P,
                       (const bf16x8*)W2P, (const bf16x8*)BsP,
                       mu_b1, mu_g, mu_be, mu_b2,
                       sg_b1, sg_g, sg_be, sg_b2, out);
}

// Round 5
// 249.382 us; speedup vs baseline: 1.2728x; 1.2033x over previous
//
#include <hip/hip_runtime.h>
#include <hip/hip_bf16.h>
#include <math.h>

#define INDIM 768
#define NROWS 32768       // 8*4096
#define KSEL  38
#define NCOLS 76
#define HID   256
#define LN_EPS 1e-5f

typedef float  f32x4  __attribute__((ext_vector_type(4)));
typedef __bf16 bf16x8 __attribute__((ext_vector_type(8)));

#define MFMA16(a,b,c) __builtin_amdgcn_mfma_f32_16x16x32_bf16((a),(b),(c),0,0,0)

// ---- workspace: all shared matrices pre-packed in MFMA B-fragment order ----
// frag value(lane, j) = M[n = nt*16 + (lane&15)][k = ks*32 + (lane>>4)*8 + j]
// stored [frag][lane][8] bf16 -> staging loads and ds reads are contiguous.
// BfP: DFT basis,  frag = kc*5 + nt   (kc 0..23, nt 0..4)   : 120 frags
// W1P: layer1 w,   frag = mlp*48 + nt*3 + ks (nt 0..15)     : 96 frags
// W2P: layer2 w,   frag = mlp*40 + nt*8 + ks (nt 0..4)      : 80 frags
// BsP: synth basis frag = nt*3 + ks  (nt 0..47)             : 144 frags
#define OFF_BFP 0
#define OFF_W1P 122880
#define OFF_W2P 221184
#define OFF_BSP 303104

__global__ void k_prep(const int* __restrict__ idxs,
                       const float* __restrict__ mu_w1, const float* __restrict__ sg_w1,
                       const float* __restrict__ mu_w2, const float* __restrict__ sg_w2,
                       __bf16* __restrict__ BfP, __bf16* __restrict__ W1P,
                       __bf16* __restrict__ W2P, __bf16* __restrict__ BsP)
{
    int tid = blockIdx.x * blockDim.x + threadIdx.x;
    int nth = gridDim.x * blockDim.x;
    const float TH = 6.28318530717958647692f / (float)INDIM;

    for (int e = tid; e < 120 * 512; e += nth) {
        int frag = e >> 9, lane = (e >> 3) & 63, j = e & 7;
        int kc = frag / 5, nt = frag % 5;
        int c = nt * 16 + (lane & 15);
        int k = kc * 32 + ((lane >> 4) << 3) + j;
        float v = 0.f;
        if (c < NCOLS) {
            int cc = (c < KSEL) ? c : c - KSEL;
            int f = idxs[cc];
            int m = (f * k) % INDIM;
            float s, co; sincosf(TH * (float)m, &s, &co);
            v = (c < KSEL) ? co : -s;
        }
        BfP[e] = (__bf16)v;
    }
    for (int e = tid; e < 96 * 512; e += nth) {
        int frag = e >> 9, lane = (e >> 3) & 63, j = e & 7;
        int mlp = frag / 48; int r = frag % 48;
        int nt = r / 3, ks = r % 3;
        int row = nt * 16 + (lane & 15);
        int k = ks * 32 + ((lane >> 4) << 3) + j;
        const float* W = mlp ? sg_w1 : mu_w1;
        W1P[e] = (__bf16)((k < NCOLS) ? W[row * NCOLS + k] : 0.f);
    }
    for (int e = tid; e < 80 * 512; e += nth) {
        int frag = e >> 9, lane = (e >> 3) & 63, j = e & 7;
        int mlp = frag / 40; int r = frag % 40;
        int nt = r / 8, ks = r % 8;
        int row = nt * 16 + (lane & 15);
        int k = ks * 32 + ((lane >> 4) << 3) + j;
        const float* W = mlp ? sg_w2 : mu_w2;
        W2P[e] = (__bf16)((row < NCOLS) ? W[row * HID + k] : 0.f);
    }
    for (int e = tid; e < 144 * 512; e += nth) {
        int frag = e >> 9, lane = (e >> 3) & 63, j = e & 7;
        int nt = frag / 3, ks = frag % 3;
        int n = nt * 16 + (lane & 15);
        int k = ks * 32 + ((lane >> 4) << 3) + j;
        float v = 0.f;
        if (k < NCOLS) {
            int cc = (k < KSEL) ? k : k - KSEL;
            int f = idxs[cc];
            int m = (f * n) % INDIM;
            float s, co; sincosf(TH * (float)m, &s, &co);
            v = ((k < KSEL) ? co : -s) * (2.0f / (float)INDIM);
        }
        BsP[e] = (__bf16)v;
    }
}

// tanh-form gelu: |err vs exact| <= ~3e-4 on gelu output -> ~5e-6 on final out.
static __device__ inline float gelu_fast(float v) {
    float u = v * (0.79788456080286535588f + 0.03567740813636141f * v * v);
    return v / (1.f + __expf(-2.f * u));   // = v * sigmoid(2u) = 0.5 v (1+tanh(u))
}

// Fused DFT -> MLPx2 -> z -> synthesis. Block = 256 thr (4 waves), 64 rows.
// Each phase's matrix is staged ONCE into a 48 KB LDS region (overlaid per
// phase), all MFMA B-operands come from ds_read_b128. ~20 barriers total,
// 40-48 MFMAs per stage. 2 blocks/CU co-resident cover barrier drains.
__global__ __launch_bounds__(256, 2) void k_fused(
    const float* __restrict__ x, const float* __restrict__ eps,
    const __bf16* __restrict__ BfG, const __bf16* __restrict__ W1G,
    const __bf16* __restrict__ W2G, const __bf16* __restrict__ BsG,
    const float* __restrict__ mu_b1, const float* __restrict__ mu_g,
    const float* __restrict__ mu_be, const float* __restrict__ mu_b2,
    const float* __restrict__ sg_b1, const float* __restrict__ sg_g,
    const float* __restrict__ sg_be, const float* __restrict__ sg_b2,
    float* __restrict__ out)
{
    __shared__ __bf16 sstage[24576];      // 48 KB staging / gelu overlay
    __shared__ __bf16 stb[4][1664];       // per-wave 16x104 transpose bufs
    int tid = threadIdx.x;
    int w = tid >> 6, lane = tid & 63, q = lane >> 4, l16 = lane & 15;
    int rbase = blockIdx.x * 64 + w * 16;
    __bf16* tb = stb[w];

    auto stage = [&](const __bf16* src, int n16) {
        for (int i = tid; i < n16; i += 256)
            *(bf16x8*)&sstage[i * 8] = *(const bf16x8*)&src[i * 8];
    };

    // ---------------- Phase 1: DFT (16 rows x 80 cols), K=768 ----------------
    f32x4 acc[5] = {};
    {
        const float* xrow = x + (size_t)(rbase + l16) * INDIM + q * 8;
        for (int c = 0; c < 3; ++c) {
            stage(BfG + (size_t)c * 40 * 512, 2560);     // 40 frags
            __syncthreads();
            #pragma unroll
            for (int kk = 0; kk < 8; ++kk) {
                int kc = c * 8 + kk;
                float4 f0 = ((const float4*)(xrow + kc * 32))[0];
                float4 f1 = ((const float4*)(xrow + kc * 32))[1];
                union { __bf16 h[8]; bf16x8 v; } a;
                a.h[0]=(__bf16)f0.x; a.h[1]=(__bf16)f0.y; a.h[2]=(__bf16)f0.z; a.h[3]=(__bf16)f0.w;
                a.h[4]=(__bf16)f1.x; a.h[5]=(__bf16)f1.y; a.h[6]=(__bf16)f1.z; a.h[7]=(__bf16)f1.w;
                #pragma unroll
                for (int nt = 0; nt < 5; ++nt) {
                    bf16x8 b = *(const bf16x8*)&sstage[(kk * 5 + nt) * 512 + lane * 8];
                    acc[nt] = MFMA16(a.v, b, acc[nt]);
                }
            }
            __syncthreads();
        }
    }
    // D-layout -> A-layout via wave-private transpose buf (stride 104)
    #pragma unroll
    for (int nt = 0; nt < 5; ++nt)
        #pragma unroll
        for (int r = 0; r < 4; ++r)
            tb[(q * 4 + r) * 104 + nt * 16 + l16] = (__bf16)acc[nt][r];
    #pragma unroll
    for (int r = 0; r < 4; ++r)
        tb[(q * 4 + r) * 104 + 80 + l16] = (__bf16)0.f;
    bf16x8 a1[3];
    #pragma unroll
    for (int ks = 0; ks < 3; ++ks)
        a1[ks] = *(const bf16x8*)&tb[l16 * 104 + ks * 32 + q * 8];

    // ---------------- Phase 2+3: MLPs (sequential, LDS-resident weights) -------
    f32x4 o2[2][5];
    #pragma unroll
    for (int mlp = 0; mlp < 2; ++mlp) {
        const float* b1 = mlp ? sg_b1 : mu_b1;
        const float* g  = mlp ? sg_g  : mu_g;
        const float* be = mlp ? sg_be : mu_be;

        // layer1: stage 48 frags (48 KB), 48 MFMAs
        stage(W1G + (size_t)mlp * 48 * 512, 3072);
        __syncthreads();
        f32x4 h[16] = {};
        #pragma unroll
        for (int nt = 0; nt < 16; ++nt)
            #pragma unroll
            for (int ks = 0; ks < 3; ++ks) {
                bf16x8 b = *(const bf16x8*)&sstage[(nt * 3 + ks) * 512 + lane * 8];
                h[nt] = MFMA16(a1[ks], b, h[nt]);
            }
        __syncthreads();   // W1 region free -> gelu overlay

        // bias + LN stats
        float s[4] = {}, ss[4] = {};
        #pragma unroll
        for (int nt = 0; nt < 16; ++nt) {
            float bb = b1[nt * 16 + l16];
            #pragma unroll
            for (int r = 0; r < 4; ++r) {
                float v = h[nt][r] + bb; h[nt][r] = v;
                s[r] += v; ss[r] += v * v;
            }
        }
        #pragma unroll
        for (int off = 1; off < 16; off <<= 1)
            #pragma unroll
            for (int r = 0; r < 4; ++r) {
                s[r] += __shfl_xor(s[r], off); ss[r] += __shfl_xor(ss[r], off);
            }
        float mean[4], rstd[4];
        #pragma unroll
        for (int r = 0; r < 4; ++r) {
            mean[r] = s[r] * (1.f / 256.f);
            rstd[r] = rsqrtf(ss[r] * (1.f / 256.f) - mean[r] * mean[r] + LN_EPS);
        }
        // LN + gelu -> wave slice of staging region (stride 264) -> a2 frags
        __bf16* gw = &sstage[w * 16 * 264];
        #pragma unroll
        for (int nt = 0; nt < 16; ++nt) {
            int i = nt * 16 + l16;
            float gv = g[i], bev = be[i];
            #pragma unroll
            for (int r = 0; r < 4; ++r)
                gw[(q * 4 + r) * 264 + i] =
                    (__bf16)gelu_fast((h[nt][r] - mean[r]) * rstd[r] * gv + bev);
        }
        bf16x8 a2[8];
        #pragma unroll
        for (int ks = 0; ks < 8; ++ks)
            a2[ks] = *(const bf16x8*)&gw[l16 * 264 + ks * 32 + q * 8];
        __syncthreads();   // gelu bufs consumed -> W2 overlay

        // layer2: stage 40 frags (40 KB), 40 MFMAs
        stage(W2G + (size_t)mlp * 40 * 512, 2560);
        __syncthreads();
        #pragma unroll
        for (int nt = 0; nt < 5; ++nt) {
            f32x4 oc = {};
            #pragma unroll
            for (int ks = 0; ks < 8; ++ks) {
                bf16x8 b = *(const bf16x8*)&sstage[(nt * 8 + ks) * 512 + lane * 8];
                oc = MFMA16(a2[ks], b, oc);
            }
            o2[mlp][nt] = oc;
        }
        __syncthreads();   // W2 region free
    }

    // ---------------- Phase 4: z = mu + eps*sg -> transpose buf ----------------
    #pragma unroll
    for (int nt = 0; nt < 5; ++nt) {
        int j = nt * 16 + l16;
        float b2m = (j < NCOLS) ? mu_b2[j] : 0.f;
        float b2s = (j < NCOLS) ? sg_b2[j] : 0.f;
        #pragma unroll
        for (int r = 0; r < 4; ++r) {
            float z = 0.f;
            if (j < NCOLS) {
                float e = eps[(size_t)(rbase + q * 4 + r) * NCOLS + j];
                z = (o2[0][nt][r] + b2m) + e * (o2[1][nt][r] + b2s);
            }
            tb[(q * 4 + r) * 104 + j] = (__bf16)z;
        }
    }
    #pragma unroll
    for (int r = 0; r < 4; ++r)
        tb[(q * 4 + r) * 104 + 80 + l16] = (__bf16)0.f;
    bf16x8 az[3];
    #pragma unroll
    for (int ks = 0; ks < 3; ++ks)
        az[ks] = *(const bf16x8*)&tb[l16 * 104 + ks * 32 + q * 8];

    // ---------------- Phase 5: synthesis, 3 chunks of 16 n-tiles ----------------
    for (int c = 0; c < 3; ++c) {
        stage(BsG + (size_t)c * 48 * 512, 3072);   // 48 frags
        __syncthreads();
        #pragma unroll
        for (int ntl = 0; ntl < 16; ++ntl) {
            f32x4 oc = {};
            #pragma unroll
            for (int ks = 0; ks < 3; ++ks) {
                bf16x8 b = *(const bf16x8*)&sstage[(ntl * 3 + ks) * 512 + lane * 8];
                oc = MFMA16(az[ks], b, oc);
            }
            int col = (c * 16 + ntl) * 16 + l16;
            #pragma unroll
            for (int r = 0; r < 4; ++r)
                out[(size_t)(rbase + q * 4 + r) * INDIM + col] = oc[r];
        }
        __syncthreads();
    }
}

extern "C" void kernel_launch(void* const* d_in, const int* in_sizes, int n_in,
                              void* d_out, int out_size, void* d_ws, size_t ws_size,
                              hipStream_t stream)
{
    const float* x     = (const float*)d_in[0];
    const float* eps   = (const float*)d_in[1];
    const int*   idxs  = (const int*)  d_in[2];
    const float* mu_w1 = (const float*)d_in[3];
    const float* mu_b1 = (const float*)d_in[4];
    const float* mu_g  = (const float*)d_in[5];
    const float* mu_be = (const float*)d_in[6];
    const float* mu_w2 = (const float*)d_in[7];
    const float* mu_b2 = (const float*)d_in[8];
    const float* sg_w1 = (const float*)d_in[9];
    const float* sg_b1 = (const float*)d_in[10];
    const float* sg_g  = (const float*)d_in[11];
    const float* sg_be = (const float*)d_in[12];
    const float* sg_w2 = (const float*)d_in[13];
    const float* sg_b2 = (const float*)d_in[14];
    float* out = (float*)d_out;

    char* ws = (char*)d_ws;
    __bf16* BfP = (__bf16*)(ws + OFF_BFP);
    __bf16* W1P = (__bf16*)(ws + OFF_W1P);
    __bf16* W2P = (__bf16*)(ws + OFF_W2P);
    __bf16* BsP = (__bf16*)(ws + OFF_BSP);

    hipLaunchKernelGGL(k_prep, dim3(1024), dim3(256), 0, stream,
                       idxs, mu_w1, sg_w1, mu_w2, sg_w2, BfP, W1P, W2P, BsP);
    hipLaunchKernelGGL(k_fused, dim3(NROWS / 64), dim3(256), 0, stream,
                       x, eps, BfP, W1P, W2P, BsP,
                       mu_b1, mu_g, mu_be, mu_b2,
                       sg_b1, sg_g, sg_be, sg_b2, out);
}

// Round 6
// 247.701 us; speedup vs baseline: 1.2815x; 1.0068x over previous
//
#include <hip/hip_runtime.h>
#include <hip/hip_bf16.h>
#include <math.h>

#define INDIM 768
#define NROWS 32768       // 8*4096
#define KSEL  38
#define NCOLS 76
#define HID   256
#define LN_EPS 1e-5f

typedef float  f32x4  __attribute__((ext_vector_type(4)));
typedef __bf16 bf16x8 __attribute__((ext_vector_type(8)));

#define MFMA16(a,b,c) __builtin_amdgcn_mfma_f32_16x16x32_bf16((a),(b),(c),0,0,0)

// ---- workspace: shared matrices pre-packed in MFMA B-fragment order ----
// frag value(lane, j) = M[n = nt*16 + (lane&15)][k = ks*32 + (lane>>4)*8 + j]
// BfP: DFT basis,  frag = kc*5 + nt   (kc 0..23, nt 0..4)   : 120 frags
// W1P: layer1 w,   frag = mlp*48 + nt*3 + ks (nt 0..15)     : 96 frags
// W2P: layer2 w,   frag = mlp*40 + nt*8 + ks (nt 0..4)      : 80 frags
// BsP: synth basis frag = nt*3 + ks  (nt 0..47)             : 144 frags
#define OFF_BFP 0
#define OFF_W1P 122880
#define OFF_W2P 221184
#define OFF_BSP 303104

__global__ void k_prep(const int* __restrict__ idxs,
                       const float* __restrict__ mu_w1, const float* __restrict__ sg_w1,
                       const float* __restrict__ mu_w2, const float* __restrict__ sg_w2,
                       __bf16* __restrict__ BfP, __bf16* __restrict__ W1P,
                       __bf16* __restrict__ W2P, __bf16* __restrict__ BsP)
{
    int tid = blockIdx.x * blockDim.x + threadIdx.x;
    int nth = gridDim.x * blockDim.x;
    const float TH = 6.28318530717958647692f / (float)INDIM;

    for (int e = tid; e < 120 * 512; e += nth) {
        int frag = e >> 9, lane = (e >> 3) & 63, j = e & 7;
        int kc = frag / 5, nt = frag % 5;
        int c = nt * 16 + (lane & 15);
        int k = kc * 32 + ((lane >> 4) << 3) + j;
        float v = 0.f;
        if (c < NCOLS) {
            int cc = (c < KSEL) ? c : c - KSEL;
            int f = idxs[cc];
            int m = (f * k) % INDIM;
            float s, co; sincosf(TH * (float)m, &s, &co);
            v = (c < KSEL) ? co : -s;
        }
        BfP[e] = (__bf16)v;
    }
    for (int e = tid; e < 96 * 512; e += nth) {
        int frag = e >> 9, lane = (e >> 3) & 63, j = e & 7;
        int mlp = frag / 48; int r = frag % 48;
        int nt = r / 3, ks = r % 3;
        int row = nt * 16 + (lane & 15);
        int k = ks * 32 + ((lane >> 4) << 3) + j;
        const float* W = mlp ? sg_w1 : mu_w1;
        W1P[e] = (__bf16)((k < NCOLS) ? W[row * NCOLS + k] : 0.f);
    }
    for (int e = tid; e < 80 * 512; e += nth) {
        int frag = e >> 9, lane = (e >> 3) & 63, j = e & 7;
        int mlp = frag / 40; int r = frag % 40;
        int nt = r / 8, ks = r % 8;
        int row = nt * 16 + (lane & 15);
        int k = ks * 32 + ((lane >> 4) << 3) + j;
        const float* W = mlp ? sg_w2 : mu_w2;
        W2P[e] = (__bf16)((row < NCOLS) ? W[row * HID + k] : 0.f);
    }
    for (int e = tid; e < 144 * 512; e += nth) {
        int frag = e >> 9, lane = (e >> 3) & 63, j = e & 7;
        int nt = frag / 3, ks = frag % 3;
        int n = nt * 16 + (lane & 15);
        int k = ks * 32 + ((lane >> 4) << 3) + j;
        float v = 0.f;
        if (k < NCOLS) {
            int cc = (k < KSEL) ? k : k - KSEL;
            int f = idxs[cc];
            int m = (f * n) % INDIM;
            float s, co; sincosf(TH * (float)m, &s, &co);
            v = ((k < KSEL) ? co : -s) * (2.0f / (float)INDIM);
        }
        BsP[e] = (__bf16)v;
    }
}

// tanh-form gelu (error vs exact ~3e-4 on gelu out -> ~5e-6 on final out)
static __device__ inline float gelu_fast(float v) {
    float u = v * (0.79788456080286535588f + 0.03567740813636141f * v * v);
    return v / (1.f + __expf(-2.f * u));
}

// Fused kernel, PAIR-SPLIT for occupancy: block = 256 thr = 4 waves = 2 row
// tiles of 16 rows; each tile is owned by a wave PAIR (p=0,1):
//   P1 DFT: K=768 split in two K=384 halves (fp32 combine via LDS)
//   P2/P3: p=0 computes the mu MLP, p=1 the sg MLP (same rows)
//   P4: z = mu + eps*sg combined via LDS
//   P5 synthesis: N=48 tiles split 24/24
// grid 1024 blocks -> 4 blocks/CU -> 16 waves/CU (4/SIMD), vs 8 before.
// LDS 24 KB/block; B-operands are packed coalesced global streams.
__global__ __launch_bounds__(256, 4) void k_fused(
    const float* __restrict__ x, const float* __restrict__ eps,
    const __bf16* __restrict__ Bf, const __bf16* __restrict__ W1f,
    const __bf16* __restrict__ W2f, const __bf16* __restrict__ Bs,
    const float* __restrict__ mu_b1, const float* __restrict__ mu_g,
    const float* __restrict__ mu_be, const float* __restrict__ mu_b2,
    const float* __restrict__ sg_b1, const float* __restrict__ sg_g,
    const float* __restrict__ sg_be, const float* __restrict__ sg_b2,
    float* __restrict__ out)
{
    __shared__ __bf16 tbuf[2][1664];   // per-tile 16x104 transpose buf
    __shared__ char   ureg[17408];     // overlay: PA [2][1280] f32 | gelu [4][2176] bf16
    float*  PA = (float*)ureg;
    __bf16* GW = (__bf16*)ureg;

    int tid = threadIdx.x;
    int w = tid >> 6, lane = tid & 63, q = lane >> 4, l16 = lane & 15;
    int t = w >> 1, p = w & 1;
    int rbase = blockIdx.x * 32 + t * 16;

    // ---------------- Phase 1: DFT, this wave does K-half p (12 kc) ----------
    f32x4 acc[5] = {};
    {
        const float* xrow = x + (size_t)(rbase + l16) * INDIM + p * 384 + q * 8;
        #pragma unroll
        for (int kk = 0; kk < 12; ++kk) {
            int kc = p * 12 + kk;
            float4 f0 = ((const float4*)(xrow + kk * 32))[0];
            float4 f1 = ((const float4*)(xrow + kk * 32))[1];
            union { __bf16 h[8]; bf16x8 v; } a;
            a.h[0]=(__bf16)f0.x; a.h[1]=(__bf16)f0.y; a.h[2]=(__bf16)f0.z; a.h[3]=(__bf16)f0.w;
            a.h[4]=(__bf16)f1.x; a.h[5]=(__bf16)f1.y; a.h[6]=(__bf16)f1.z; a.h[7]=(__bf16)f1.w;
            #pragma unroll
            for (int nt = 0; nt < 5; ++nt) {
                bf16x8 b = *(const bf16x8*)&Bf[(size_t)((kc * 5 + nt) * 64 + lane) * 8];
                acc[nt] = MFMA16(a.v, b, acc[nt]);
            }
        }
    }
    // combine halves (fp32) + transpose to A-layout in tbuf[t]
    if (p == 1) {
        #pragma unroll
        for (int nt = 0; nt < 5; ++nt)
            #pragma unroll
            for (int r = 0; r < 4; ++r)
                PA[t * 1280 + (q * 4 + r) * 80 + nt * 16 + l16] = acc[nt][r];
    }
    __syncthreads();
    if (p == 0) {
        #pragma unroll
        for (int nt = 0; nt < 5; ++nt)
            #pragma unroll
            for (int r = 0; r < 4; ++r) {
                float v = acc[nt][r] + PA[t * 1280 + (q * 4 + r) * 80 + nt * 16 + l16];
                tbuf[t][(q * 4 + r) * 104 + nt * 16 + l16] = (__bf16)v;
            }
        #pragma unroll
        for (int r = 0; r < 4; ++r)
            tbuf[t][(q * 4 + r) * 104 + 80 + l16] = (__bf16)0.f;
    }
    __syncthreads();
    bf16x8 a1[3];
    #pragma unroll
    for (int ks = 0; ks < 3; ++ks)
        a1[ks] = *(const bf16x8*)&tbuf[t][l16 * 104 + ks * 32 + q * 8];

    // ---------------- Phase 2: this wave's MLP (mlp = p), layer1 -------------
    const float* b1 = p ? sg_b1 : mu_b1;
    const float* g  = p ? sg_g  : mu_g;
    const float* be = p ? sg_be : mu_be;

    f32x4 h[16] = {};
    #pragma unroll
    for (int nt = 0; nt < 16; ++nt)
        #pragma unroll
        for (int ks = 0; ks < 3; ++ks) {
            bf16x8 b = *(const bf16x8*)&W1f[(size_t)((p * 48 + nt * 3 + ks) * 64 + lane) * 8];
            h[nt] = MFMA16(a1[ks], b, h[nt]);
        }
    float s[4] = {}, ss[4] = {};
    #pragma unroll
    for (int nt = 0; nt < 16; ++nt) {
        float bb = b1[nt * 16 + l16];
        #pragma unroll
        for (int r = 0; r < 4; ++r) {
            float v = h[nt][r] + bb; h[nt][r] = v;
            s[r] += v; ss[r] += v * v;
        }
    }
    #pragma unroll
    for (int off = 1; off < 16; off <<= 1)
        #pragma unroll
        for (int r = 0; r < 4; ++r) {
            s[r] += __shfl_xor(s[r], off); ss[r] += __shfl_xor(ss[r], off);
        }
    float mean[4], rstd[4];
    #pragma unroll
    for (int r = 0; r < 4; ++r) {
        mean[r] = s[r] * (1.f / 256.f);
        rstd[r] = rsqrtf(ss[r] * (1.f / 256.f) - mean[r] * mean[r] + LN_EPS);
    }
    // LN + gelu -> wave-private half-buffer (stride 136), two K-halves
    __bf16* gw = &GW[w * 2176];
    bf16x8 a2[8];
    #pragma unroll
    for (int half = 0; half < 2; ++half) {
        #pragma unroll
        for (int ntl = 0; ntl < 8; ++ntl) {
            int nt = half * 8 + ntl;
            int i = nt * 16 + l16;
            float gv = g[i], bev = be[i];
            #pragma unroll
            for (int r = 0; r < 4; ++r)
                gw[(q * 4 + r) * 136 + ntl * 16 + l16] =
                    (__bf16)gelu_fast((h[nt][r] - mean[r]) * rstd[r] * gv + bev);
        }
        #pragma unroll
        for (int ks = 0; ks < 4; ++ks)
            a2[half * 4 + ks] = *(const bf16x8*)&gw[l16 * 136 + ks * 32 + q * 8];
    }

    // ---------------- Phase 3: layer2 (this wave's MLP) ----------------------
    f32x4 o[5] = {};
    #pragma unroll
    for (int nt = 0; nt < 5; ++nt)
        #pragma unroll
        for (int ks = 0; ks < 8; ++ks) {
            bf16x8 b = *(const bf16x8*)&W2f[(size_t)((p * 40 + nt * 8 + ks) * 64 + lane) * 8];
            o[nt] = MFMA16(a2[ks], b, o[nt]);
        }

    // ---------------- Phase 4: z = (mu+b2m) + eps*(sg+b2s) -------------------
    __syncthreads();   // all waves done reading GW -> PA overlay is safe
    float ev[5][4];
    if (p == 0) {
        // publish o_mu
        #pragma unroll
        for (int nt = 0; nt < 5; ++nt)
            #pragma unroll
            for (int r = 0; r < 4; ++r)
                PA[t * 1280 + (q * 4 + r) * 80 + nt * 16 + l16] = o[nt][r];
    } else {
        // prefetch eps
        #pragma unroll
        for (int nt = 0; nt < 5; ++nt) {
            int j = nt * 16 + l16;
            #pragma unroll
            for (int r = 0; r < 4; ++r)
                ev[nt][r] = (j < NCOLS)
                    ? eps[(size_t)(rbase + q * 4 + r) * NCOLS + j] : 0.f;
        }
    }
    __syncthreads();
    if (p == 1) {
        #pragma unroll
        for (int nt = 0; nt < 5; ++nt) {
            int j = nt * 16 + l16;
            float b2m = (j < NCOLS) ? mu_b2[j] : 0.f;
            float b2s = (j < NCOLS) ? sg_b2[j] : 0.f;
            #pragma unroll
            for (int r = 0; r < 4; ++r) {
                float z = 0.f;
                if (j < NCOLS) {
                    float omu = PA[t * 1280 + (q * 4 + r) * 80 + j];
                    z = (omu + b2m) + ev[nt][r] * (o[nt][r] + b2s);
                }
                tbuf[t][(q * 4 + r) * 104 + j] = (__bf16)z;
            }
        }
        #pragma unroll
        for (int r = 0; r < 4; ++r)
            tbuf[t][(q * 4 + r) * 104 + 80 + l16] = (__bf16)0.f;
    }
    __syncthreads();
    bf16x8 az[3];
    #pragma unroll
    for (int ks = 0; ks < 3; ++ks)
        az[ks] = *(const bf16x8*)&tbuf[t][l16 * 104 + ks * 32 + q * 8];

    // ---------------- Phase 5: synthesis, this wave does 24 n-tiles ----------
    #pragma unroll 6
    for (int k = 0; k < 24; ++k) {
        int nt = p * 24 + k;
        f32x4 oc = {};
        #pragma unroll
        for (int ks = 0; ks < 3; ++ks) {
            bf16x8 b = *(const bf16x8*)&Bs[(size_t)((nt * 3 + ks) * 64 + lane) * 8];
            oc = MFMA16(az[ks], b, oc);
        }
        #pragma unroll
        for (int r = 0; r < 4; ++r)
            out[(size_t)(rbase + q * 4 + r) * INDIM + nt * 16 + l16] = oc[r];
    }
}

extern "C" void kernel_launch(void* const* d_in, const int* in_sizes, int n_in,
                              void* d_out, int out_size, void* d_ws, size_t ws_size,
                              hipStream_t stream)
{
    const float* x     = (const float*)d_in[0];
    const float* eps   = (const float*)d_in[1];
    const int*   idxs  = (const int*)  d_in[2];
    const float* mu_w1 = (const float*)d_in[3];
    const float* mu_b1 = (const float*)d_in[4];
    const float* mu_g  = (const float*)d_in[5];
    const float* mu_be = (const float*)d_in[6];
    const float* mu_w2 = (const float*)d_in[7];
    const float* mu_b2 = (const float*)d_in[8];
    const float* sg_w1 = (const float*)d_in[9];
    const float* sg_b1 = (const float*)d_in[10];
    const float* sg_g  = (const float*)d_in[11];
    const float* sg_be = (const float*)d_in[12];
    const float* sg_w2 = (const float*)d_in[13];
    const float* sg_b2 = (const float*)d_in[14];
    float* out = (float*)d_out;

    char* ws = (char*)d_ws;
    __bf16* BfP = (__bf16*)(ws + OFF_BFP);
    __bf16* W1P = (__bf16*)(ws + OFF_W1P);
    __bf16* W2P = (__bf16*)(ws + OFF_W2P);
    __bf16* BsP = (__bf16*)(ws + OFF_BSP);

    hipLaunchKernelGGL(k_prep, dim3(1024), dim3(256), 0, stream,
                       idxs, mu_w1, sg_w1, mu_w2, sg_w2, BfP, W1P, W2P, BsP);
    hipLaunchKernelGGL(k_fused, dim3(NROWS / 32), dim3(256), 0, stream,
                       x, eps, BfP, W1P, W2P, BsP,
                       mu_b1, mu_g, mu_be, mu_b2,
                       sg_b1, sg_g, sg_be, sg_b2, out);
}